// Round 1
// baseline (554.404 us; speedup 1.0000x reference)
//
#include <hip/hip_runtime.h>

#define NPTS   4096
#define KNN    16
#define BLK    256
#define CHUNKS (NPTS / BLK)   // 16
#define EPSF   1e-10f

__global__ __launch_bounds__(BLK) void knn_stretch_kernel(
    const float* __restrict__ pref, const float* __restrict__ ppred,
    float* __restrict__ out, float scale)
{
    __shared__ float xs[NPTS], ys[NPTS], zs[NPTS];
    __shared__ float wsum[BLK / 64];

    const int b     = blockIdx.x / CHUNKS;
    const int chunk = blockIdx.x % CHUNKS;
    const float* prb = pref  + (size_t)b * NPTS * 3;
    const float* ppb = ppred + (size_t)b * NPTS * 3;

    // Stage ref points for this batch into LDS (SoA).
    for (int p = threadIdx.x; p < NPTS; p += BLK) {
        float x = prb[3 * p + 0];
        float y = prb[3 * p + 1];
        float z = prb[3 * p + 2];
        xs[p] = x; ys[p] = y; zs[p] = z;
    }
    __syncthreads();

    const int i = chunk * BLK + threadIdx.x;   // this lane's query point
    const float qx = xs[i], qy = ys[i], qz = zs[i];

    // Sorted (ascending) top-16 of packed keys: [d2 bits (hi 20)] | [idx (lo 12)].
    unsigned arr[KNN];
#pragma unroll
    for (int k = 0; k < KNN; ++k) arr[k] = 0xFFFFFFFFu;

#pragma unroll 4
    for (int j = 0; j < NPTS; ++j) {
        float dx = xs[j] - qx;
        float dy = ys[j] - qy;
        float dz = zs[j] - qz;
        float d2 = dx * dx + dy * dy + dz * dz;
        unsigned key = (__float_as_uint(d2) & 0xFFFFF000u) | (unsigned)j;
        key = (j == i) ? 0xFFFFFFFFu : key;   // exclude self
        if (key < arr[KNN - 1]) {
            unsigned c = key;
#pragma unroll
            for (int k = 0; k < KNN; ++k) {
                unsigned lo = (c < arr[k]) ? c : arr[k];
                unsigned hi = (c < arr[k]) ? arr[k] : c;
                arr[k] = lo;
                c = hi;
            }
        }
    }

    // Gather neighbors, compute stretch terms.
    const float qpx = ppb[3 * i + 0];
    const float qpy = ppb[3 * i + 1];
    const float qpz = ppb[3 * i + 2];

    float sum = 0.f;
#pragma unroll
    for (int k = 0; k < KNN; ++k) {
        int idx = (int)(arr[k] & 0xFFFu);
        float rx = xs[idx] - qx;
        float ry = ys[idx] - qy;
        float rz = zs[idx] - qz;
        float dref = sqrtf(rx * rx + ry * ry + rz * rz);
        float ax = ppb[3 * idx + 0] - qpx;
        float ay = ppb[3 * idx + 1] - qpy;
        float az = ppb[3 * idx + 2] - qpz;
        float dpred = sqrtf(ax * ax + ay * ay + az * az);
        float s = dpred / (dref + EPSF) - 1.0f;
        sum += fmaxf(s, 0.0f);
    }

    // Wave reduce (64 lanes), then block reduce, then one atomic per block.
    for (int off = 32; off > 0; off >>= 1) sum += __shfl_down(sum, off);
    if ((threadIdx.x & 63) == 0) wsum[threadIdx.x >> 6] = sum;
    __syncthreads();
    if (threadIdx.x == 0) {
        float t = 0.f;
#pragma unroll
        for (int w = 0; w < BLK / 64; ++w) t += wsum[w];
        atomicAdd(out, t * scale);
    }
}

extern "C" void kernel_launch(void* const* d_in, const int* in_sizes, int n_in,
                              void* d_out, int out_size, void* d_ws, size_t ws_size,
                              hipStream_t stream) {
    const float* pref  = (const float*)d_in[0];
    const float* ppred = (const float*)d_in[1];
    float* out = (float*)d_out;

    const int B = in_sizes[0] / (NPTS * 3);
    const float scale = 1.0f / ((float)B * (float)NPTS * (float)KNN);

    hipMemsetAsync(d_out, 0, sizeof(float), stream);
    knn_stretch_kernel<<<dim3(B * CHUNKS), dim3(BLK), 0, stream>>>(pref, ppred, out, scale);
}

// Round 2
// 245.151 us; speedup vs baseline: 2.2615x; 2.2615x over previous
//
#include <hip/hip_runtime.h>

#define NPTS   4096
#define KNN    16
#define BLK    256
#define NSEG   8
#define SEGPTS (NPTS / NSEG)      // 512
#define CHUNKS (NPTS / BLK)       // 16
#define EPSF   1e-10f

// ---------------- Pass 1: per-segment exact top-16 ----------------
// grid = B * CHUNKS * NSEG blocks, 256 threads. Each lane owns one query,
// scans this block's 512-candidate segment, writes 16 packed keys to ws.
// key = (d2_bits & 0xFFFFF000) | global_idx  (12 idx bits, keys unique,
// uint order == d2 order up to 2^-11 relative ties; distances recomputed
// exactly later so effect on the mean is negligible).
__global__ __launch_bounds__(BLK) void knn_seg_kernel(
    const float* __restrict__ pref, unsigned* __restrict__ ws)
{
    __shared__ float4 cand[SEGPTS];   // 8 KB

    const int blocks_per_b = CHUNKS * NSEG;
    const int b     = blockIdx.x / blocks_per_b;
    const int rem   = blockIdx.x % blocks_per_b;
    const int chunk = rem / NSEG;
    const int seg   = rem % NSEG;

    const float* prb = pref + (size_t)b * NPTS * 3;
    const int segbase = seg * SEGPTS;

    for (int p = threadIdx.x; p < SEGPTS; p += BLK) {
        int g = segbase + p;
        cand[p] = make_float4(prb[3 * g + 0], prb[3 * g + 1], prb[3 * g + 2], 0.f);
    }
    __syncthreads();

    const int i = chunk * BLK + threadIdx.x;   // query index within batch
    const float qx = prb[3 * i + 0];
    const float qy = prb[3 * i + 1];
    const float qz = prb[3 * i + 2];

    unsigned arr[KNN];
#pragma unroll
    for (int k = 0; k < KNN; ++k) arr[k] = 0xFFFFFFFFu;

#pragma unroll 2
    for (int jj = 0; jj < SEGPTS; ++jj) {
        float4 c4 = cand[jj];
        float dx = c4.x - qx;
        float dy = c4.y - qy;
        float dz = c4.z - qz;
        float d2 = dx * dx + dy * dy + dz * dz;
        int j = segbase + jj;
        unsigned key = (__float_as_uint(d2) & 0xFFFFF000u) | (unsigned)j;
        key = (j == i) ? 0xFFFFFFFFu : key;
        if (key < arr[KNN - 1]) {
            unsigned c = key;
#pragma unroll
            for (int k = 0; k < KNN; ++k) {
                unsigned lo = (c < arr[k]) ? c : arr[k];
                unsigned hi = (c < arr[k]) ? arr[k] : c;
                arr[k] = lo;
                c = hi;
            }
        }
    }

    // ws layout [b][s][k][i] -> coalesced stores (lanes = consecutive i).
    unsigned* wq = ws + ((((size_t)b * NSEG + seg) * KNN) * NPTS) + i;
#pragma unroll
    for (int k = 0; k < KNN; ++k) wq[(size_t)k * NPTS] = arr[k];
}

// ---------------- Pass 2: merge segments + stretch + reduce ----------------
__global__ __launch_bounds__(BLK) void knn_merge_kernel(
    const float* __restrict__ pref, const float* __restrict__ ppred,
    const unsigned* __restrict__ ws, float* __restrict__ out, float scale)
{
    __shared__ float wsum[BLK / 64];

    const int q = blockIdx.x * BLK + threadIdx.x;   // global query id
    const int b = q / NPTS;
    const int i = q % NPTS;

    const unsigned* wb = ws + (size_t)b * NSEG * KNN * NPTS + i;

    unsigned arr[KNN];
#pragma unroll
    for (int k = 0; k < KNN; ++k) arr[k] = wb[(size_t)k * NPTS];  // seg 0, sorted

    for (int s = 1; s < NSEG; ++s) {
        const unsigned* wl = wb + (size_t)s * KNN * NPTS;
#pragma unroll
        for (int k2 = 0; k2 < KNN; ++k2) {
            unsigned key = wl[(size_t)k2 * NPTS];
            if (key < arr[KNN - 1]) {
                unsigned c = key;
#pragma unroll
                for (int k = 0; k < KNN; ++k) {
                    unsigned lo = (c < arr[k]) ? c : arr[k];
                    unsigned hi = (c < arr[k]) ? arr[k] : c;
                    arr[k] = lo;
                    c = hi;
                }
            }
        }
    }

    const float* prb = pref  + (size_t)b * NPTS * 3;
    const float* ppb = ppred + (size_t)b * NPTS * 3;
    const float qx = prb[3 * i + 0], qy = prb[3 * i + 1], qz = prb[3 * i + 2];
    const float px = ppb[3 * i + 0], py = ppb[3 * i + 1], pz = ppb[3 * i + 2];

    float sum = 0.f;
#pragma unroll
    for (int k = 0; k < KNN; ++k) {
        int idx = (int)(arr[k] & 0xFFFu);
        float rx = prb[3 * idx + 0] - qx;
        float ry = prb[3 * idx + 1] - qy;
        float rz = prb[3 * idx + 2] - qz;
        float dref = sqrtf(rx * rx + ry * ry + rz * rz);
        float ax = ppb[3 * idx + 0] - px;
        float ay = ppb[3 * idx + 1] - py;
        float az = ppb[3 * idx + 2] - pz;
        float dpred = sqrtf(ax * ax + ay * ay + az * az);
        sum += fmaxf(dpred / (dref + EPSF) - 1.0f, 0.0f);
    }

    for (int off = 32; off > 0; off >>= 1) sum += __shfl_down(sum, off);
    if ((threadIdx.x & 63) == 0) wsum[threadIdx.x >> 6] = sum;
    __syncthreads();
    if (threadIdx.x == 0) {
        float t = 0.f;
#pragma unroll
        for (int w = 0; w < BLK / 64; ++w) t += wsum[w];
        atomicAdd(out, t * scale);
    }
}

// ---------------- Fallback (R1 monolithic kernel) if ws too small ----------
__global__ __launch_bounds__(BLK) void knn_stretch_kernel(
    const float* __restrict__ pref, const float* __restrict__ ppred,
    float* __restrict__ out, float scale)
{
    __shared__ float xs[NPTS], ys[NPTS], zs[NPTS];
    __shared__ float wsum[BLK / 64];

    const int b     = blockIdx.x / CHUNKS;
    const int chunk = blockIdx.x % CHUNKS;
    const float* prb = pref  + (size_t)b * NPTS * 3;
    const float* ppb = ppred + (size_t)b * NPTS * 3;

    for (int p = threadIdx.x; p < NPTS; p += BLK) {
        xs[p] = prb[3 * p + 0]; ys[p] = prb[3 * p + 1]; zs[p] = prb[3 * p + 2];
    }
    __syncthreads();

    const int i = chunk * BLK + threadIdx.x;
    const float qx = xs[i], qy = ys[i], qz = zs[i];

    unsigned arr[KNN];
#pragma unroll
    for (int k = 0; k < KNN; ++k) arr[k] = 0xFFFFFFFFu;

#pragma unroll 4
    for (int j = 0; j < NPTS; ++j) {
        float dx = xs[j] - qx, dy = ys[j] - qy, dz = zs[j] - qz;
        float d2 = dx * dx + dy * dy + dz * dz;
        unsigned key = (__float_as_uint(d2) & 0xFFFFF000u) | (unsigned)j;
        key = (j == i) ? 0xFFFFFFFFu : key;
        if (key < arr[KNN - 1]) {
            unsigned c = key;
#pragma unroll
            for (int k = 0; k < KNN; ++k) {
                unsigned lo = (c < arr[k]) ? c : arr[k];
                unsigned hi = (c < arr[k]) ? arr[k] : c;
                arr[k] = lo; c = hi;
            }
        }
    }

    const float qpx = ppb[3 * i + 0], qpy = ppb[3 * i + 1], qpz = ppb[3 * i + 2];
    float sum = 0.f;
#pragma unroll
    for (int k = 0; k < KNN; ++k) {
        int idx = (int)(arr[k] & 0xFFFu);
        float rx = xs[idx] - qx, ry = ys[idx] - qy, rz = zs[idx] - qz;
        float dref = sqrtf(rx * rx + ry * ry + rz * rz);
        float ax = ppb[3 * idx + 0] - qpx, ay = ppb[3 * idx + 1] - qpy, az = ppb[3 * idx + 2] - qpz;
        float dpred = sqrtf(ax * ax + ay * ay + az * az);
        sum += fmaxf(dpred / (dref + EPSF) - 1.0f, 0.0f);
    }

    for (int off = 32; off > 0; off >>= 1) sum += __shfl_down(sum, off);
    if ((threadIdx.x & 63) == 0) wsum[threadIdx.x >> 6] = sum;
    __syncthreads();
    if (threadIdx.x == 0) {
        float t = 0.f;
#pragma unroll
        for (int w = 0; w < BLK / 64; ++w) t += wsum[w];
        atomicAdd(out, t * scale);
    }
}

extern "C" void kernel_launch(void* const* d_in, const int* in_sizes, int n_in,
                              void* d_out, int out_size, void* d_ws, size_t ws_size,
                              hipStream_t stream) {
    const float* pref  = (const float*)d_in[0];
    const float* ppred = (const float*)d_in[1];
    float* out = (float*)d_out;

    const int B = in_sizes[0] / (NPTS * 3);
    const float scale = 1.0f / ((float)B * (float)NPTS * (float)KNN);

    hipMemsetAsync(d_out, 0, sizeof(float), stream);

    const size_t need = (size_t)B * NSEG * KNN * NPTS * sizeof(unsigned);
    if (ws_size >= need) {
        unsigned* ws = (unsigned*)d_ws;
        knn_seg_kernel<<<dim3(B * CHUNKS * NSEG), dim3(BLK), 0, stream>>>(pref, ws);
        knn_merge_kernel<<<dim3(B * NPTS / BLK), dim3(BLK), 0, stream>>>(pref, ppred, ws, out, scale);
    } else {
        knn_stretch_kernel<<<dim3(B * CHUNKS), dim3(BLK), 0, stream>>>(pref, ppred, out, scale);
    }
}

// Round 3
// 179.949 us; speedup vs baseline: 3.0809x; 1.3623x over previous
//
#include <hip/hip_runtime.h>

#define NPTS 4096
#define KNN  16
#define K1   17          // KNN + self
#define BLK  256
#define WPB  4           // waves per block (one query per wave)
#define EPSF 1e-10f

__device__ __forceinline__ unsigned umin_(unsigned a, unsigned b) { return a < b ? a : b; }
__device__ __forceinline__ unsigned umax_(unsigned a, unsigned b) { return a < b ? b : a; }

// One wave per query. Lanes scan 64 candidates/iter for the SAME query.
// Lane-sliced sorted top-17 of packed keys (d2 high 20 bits | idx 12 bits);
// element 0 is always self (d2 == +0.0 exactly -> key = i = minimum).
__global__ __launch_bounds__(BLK) void knn_main_kernel(
    const float* __restrict__ pref, const float* __restrict__ ppred,
    float* __restrict__ partials)
{
    __shared__ float xs[NPTS], ys[NPTS], zs[NPTS];   // 48 KB
    __shared__ float wsum[WPB];

    const int w    = threadIdx.x >> 6;
    const int lane = threadIdx.x & 63;
    const int q    = blockIdx.x * WPB + w;   // global query id
    const int b    = q >> 12;                 // / NPTS
    const int i    = q & (NPTS - 1);

    // Stage this batch's ref points into LDS SoA (block-uniform batch).
    const float* prb = pref + (size_t)b * NPTS * 3;
    for (int p = threadIdx.x; p < NPTS; p += BLK) {
        xs[p] = prb[3 * p + 0];
        ys[p] = prb[3 * p + 1];
        zs[p] = prb[3 * p + 2];
    }
    __syncthreads();

    const float qx = xs[i], qy = ys[i], qz = zs[i];

    // ---- Bootstrap: bitonic-sort the first 64 candidate keys across lanes.
    unsigned arr;
    {
        float dx = xs[lane] - qx, dy = ys[lane] - qy, dz = zs[lane] - qz;
        float d2 = dx * dx + dy * dy + dz * dz;
        arr = (__float_as_uint(d2) & 0xFFFFF000u) | (unsigned)lane;
    }
#pragma unroll
    for (int k = 2; k <= 64; k <<= 1) {
#pragma unroll
        for (int j = k >> 1; j > 0; j >>= 1) {
            unsigned other = __shfl_xor(arr, j);
            bool takeMin = (((lane & j) == 0) == ((lane & k) == 0));
            unsigned mn = umin_(arr, other), mx = umax_(arr, other);
            arr = takeMin ? mn : mx;
        }
    }
    unsigned thr = (unsigned)__builtin_amdgcn_readlane((int)arr, K1 - 1);

    // ---- Main scan: 63 iterations x 64 candidates.
#pragma unroll 2
    for (int it = 1; it < NPTS / 64; ++it) {
        int j = it * 64 + lane;
        float dx = xs[j] - qx, dy = ys[j] - qy, dz = zs[j] - qz;
        float d2 = dx * dx + dy * dy + dz * dz;
        unsigned key = (__float_as_uint(d2) & 0xFFFFF000u) | (unsigned)j;

        unsigned long long m = __ballot(key < thr);
        if (m) {
            do {
                int l = __ffsll(m) - 1;
                m &= m - 1;
                unsigned kk = (unsigned)__builtin_amdgcn_readlane((int)key, l);
                if (kk < thr) {
                    // parallel insert into lane-sliced sorted array (lanes 0..16)
                    unsigned long long lt = __ballot(arr < kk) & 0x1FFFFull;
                    int pos = __popcll(lt);
                    unsigned up = __shfl_up(arr, 1);
                    arr = (lane == pos) ? kk : ((lane > pos) ? up : arr);
                    thr = (unsigned)__builtin_amdgcn_readlane((int)arr, K1 - 1);
                }
            } while (m);
        }
    }

    // ---- Epilogue: lanes 1..16 hold the 16 nearest neighbors.
    float s = 0.f;
    if (lane >= 1 && lane <= KNN) {
        int idx = (int)(arr & 0xFFFu);
        float rx = xs[idx] - qx, ry = ys[idx] - qy, rz = zs[idx] - qz;
        float dref = sqrtf(rx * rx + ry * ry + rz * rz);

        const float* ppb = ppred + (size_t)b * NPTS * 3;
        float px = ppb[3 * i + 0],  py = ppb[3 * i + 1],  pz = ppb[3 * i + 2];
        float ax = ppb[3 * idx + 0] - px;
        float ay = ppb[3 * idx + 1] - py;
        float az = ppb[3 * idx + 2] - pz;
        float dpred = sqrtf(ax * ax + ay * ay + az * az);
        s = fmaxf(dpred / (dref + EPSF) - 1.0f, 0.0f);
    }
    for (int off = 32; off > 0; off >>= 1) s += __shfl_down(s, off);
    if (lane == 0) wsum[w] = s;
    __syncthreads();
    if (threadIdx.x == 0)
        partials[blockIdx.x] = (wsum[0] + wsum[1]) + (wsum[2] + wsum[3]);
}

// Deterministic single-block final reduction.
__global__ __launch_bounds__(BLK) void reduce_kernel(
    const float* __restrict__ partials, int n, float* __restrict__ out, float scale)
{
    __shared__ float wsum[BLK / 64];
    float s = 0.f;
    for (int idx = threadIdx.x; idx < n; idx += BLK) s += partials[idx];
    for (int off = 32; off > 0; off >>= 1) s += __shfl_down(s, off);
    if ((threadIdx.x & 63) == 0) wsum[threadIdx.x >> 6] = s;
    __syncthreads();
    if (threadIdx.x == 0)
        out[0] = ((wsum[0] + wsum[1]) + (wsum[2] + wsum[3])) * scale;
}

extern "C" void kernel_launch(void* const* d_in, const int* in_sizes, int n_in,
                              void* d_out, int out_size, void* d_ws, size_t ws_size,
                              hipStream_t stream) {
    const float* pref  = (const float*)d_in[0];
    const float* ppred = (const float*)d_in[1];
    float* out = (float*)d_out;

    const int B = in_sizes[0] / (NPTS * 3);
    const int nblocks = B * NPTS / WPB;
    const float scale = 1.0f / ((float)B * (float)NPTS * (float)KNN);

    float* partials = (float*)d_ws;
    knn_main_kernel<<<dim3(nblocks), dim3(BLK), 0, stream>>>(pref, ppred, partials);
    reduce_kernel<<<dim3(1), dim3(BLK), 0, stream>>>(partials, nblocks, out, scale);
}

// Round 4
// 102.154 us; speedup vs baseline: 5.4272x; 1.7616x over previous
//
#include <hip/hip_runtime.h>

#define NPTS 4096
#define KNN  16
#define K1   17          // KNN + self
#define BLK  512
#define WPB  (BLK / 64)  // 8 waves per block, one query per wave
#define EPSF 1e-10f

__device__ __forceinline__ unsigned umin_(unsigned a, unsigned b) { return a < b ? a : b; }
__device__ __forceinline__ unsigned umax_(unsigned a, unsigned b) { return a < b ? b : a; }

// One wave per query; 64 lanes scan 64 candidates/iter for the SAME query.
// Lane-sliced sorted top-17 packed keys (d2 high 20 bits | idx 12 bits);
// self has d2 == +0.0 exactly (direct-diff arithmetic) -> key = i = minimum.
__global__ __launch_bounds__(BLK, 6) void knn_main_kernel(
    const float* __restrict__ pref, const float* __restrict__ ppred,
    float* __restrict__ partials)
{
    __shared__ float2 xy[NPTS];     // 32 KB
    __shared__ float  zz[NPTS];     // 16 KB
    __shared__ float  wsum[WPB];

    const int w    = threadIdx.x >> 6;
    const int lane = threadIdx.x & 63;
    const int q    = blockIdx.x * WPB + w;   // global query id
    const int b    = q >> 12;                 // / NPTS
    const int i    = q & (NPTS - 1);

    const float* prb = pref + (size_t)b * NPTS * 3;
    for (int p = threadIdx.x; p < NPTS; p += BLK) {
        xy[p] = make_float2(prb[3 * p + 0], prb[3 * p + 1]);
        zz[p] = prb[3 * p + 2];
    }
    __syncthreads();

    const float2 qv = xy[i];
    const float qx = qv.x, qy = qv.y, qz = zz[i];

    // ---- Bootstrap: bitonic sort of first 64 candidate keys across lanes.
    unsigned arr;
    {
        float2 c = xy[lane];
        float dx = c.x - qx, dy = c.y - qy, dz = zz[lane] - qz;
        float d2 = dx * dx + dy * dy + dz * dz;
        arr = (__float_as_uint(d2) & 0xFFFFF000u) | (unsigned)lane;
    }
#pragma unroll
    for (int k = 2; k <= 64; k <<= 1) {
#pragma unroll
        for (int j = k >> 1; j > 0; j >>= 1) {
            unsigned other = __shfl_xor(arr, j);
            bool takeMin = (((lane & j) == 0) == ((lane & k) == 0));
            unsigned mn = umin_(arr, other), mx = umax_(arr, other);
            arr = takeMin ? mn : mx;
        }
    }
    unsigned thr = (unsigned)__builtin_amdgcn_readlane((int)arr, K1 - 1);

    // ---- Main scan: 63 batches x 64 candidates, stale-threshold events.
#pragma unroll 4
    for (int it = 1; it < NPTS / 64; ++it) {
        int j = it * 64 + lane;
        float2 c = xy[j];
        float cz = zz[j];
        float dx = c.x - qx, dy = c.y - qy, dz = cz - qz;
        float d2 = dx * dx + dy * dy + dz * dz;
        unsigned key = (__float_as_uint(d2) & 0xFFFFF000u) | (unsigned)j;

        unsigned long long m = __ballot(key < thr);   // thr stale for whole batch: safe
        if (m) {
            do {
                int l = __ffsll(m) - 1;
                m &= m - 1;
                unsigned kk = (unsigned)__builtin_amdgcn_readlane((int)key, l);
                // insert into lane-sliced sorted array (lanes 0..16); if kk is
                // worse than arr[16], pos lands >= 17 (garbage lanes): harmless.
                unsigned long long lt = __ballot(arr < kk) & 0x1FFFFull;
                int pos = __popcll(lt);
                unsigned up = __shfl_up(arr, 1);
                arr = (lane == pos) ? kk : ((lane > pos) ? up : arr);
            } while (m);
            thr = (unsigned)__builtin_amdgcn_readlane((int)arr, K1 - 1);
        }
    }

    // ---- Epilogue: lanes 1..16 hold the 16 nearest neighbors (lane 0 = self).
    float s = 0.f;
    if (lane >= 1 && lane <= KNN) {
        int idx = (int)(arr & 0xFFFu);
        float2 rc = xy[idx];
        float rx = rc.x - qx, ry = rc.y - qy, rz = zz[idx] - qz;
        float dref = sqrtf(rx * rx + ry * ry + rz * rz);

        const float* ppb = ppred + (size_t)b * NPTS * 3;
        float px = ppb[3 * i + 0], py = ppb[3 * i + 1], pz = ppb[3 * i + 2];
        float ax = ppb[3 * idx + 0] - px;
        float ay = ppb[3 * idx + 1] - py;
        float az = ppb[3 * idx + 2] - pz;
        float dpred = sqrtf(ax * ax + ay * ay + az * az);
        s = fmaxf(dpred / (dref + EPSF) - 1.0f, 0.0f);
    }
    for (int off = 32; off > 0; off >>= 1) s += __shfl_down(s, off);
    if (lane == 0) wsum[w] = s;
    __syncthreads();
    if (threadIdx.x == 0) {
        float t = 0.f;
#pragma unroll
        for (int k = 0; k < WPB; ++k) t += wsum[k];
        partials[blockIdx.x] = t;
    }
}

// Deterministic single-block final reduction.
__global__ __launch_bounds__(256) void reduce_kernel(
    const float* __restrict__ partials, int n, float* __restrict__ out, float scale)
{
    __shared__ float wsum[4];
    float s = 0.f;
    for (int idx = threadIdx.x; idx < n; idx += 256) s += partials[idx];
    for (int off = 32; off > 0; off >>= 1) s += __shfl_down(s, off);
    if ((threadIdx.x & 63) == 0) wsum[threadIdx.x >> 6] = s;
    __syncthreads();
    if (threadIdx.x == 0)
        out[0] = ((wsum[0] + wsum[1]) + (wsum[2] + wsum[3])) * scale;
}

extern "C" void kernel_launch(void* const* d_in, const int* in_sizes, int n_in,
                              void* d_out, int out_size, void* d_ws, size_t ws_size,
                              hipStream_t stream) {
    const float* pref  = (const float*)d_in[0];
    const float* ppred = (const float*)d_in[1];
    float* out = (float*)d_out;

    const int B = in_sizes[0] / (NPTS * 3);
    const int nblocks = B * NPTS / WPB;
    const float scale = 1.0f / ((float)B * (float)NPTS * (float)KNN);

    float* partials = (float*)d_ws;
    knn_main_kernel<<<dim3(nblocks), dim3(BLK), 0, stream>>>(pref, ppred, partials);
    reduce_kernel<<<dim3(1), dim3(256), 0, stream>>>(partials, nblocks, out, scale);
}